// Round 1
// baseline (1096.820 us; speedup 1.0000x reference)
//
#include <hip/hip_runtime.h>

// BaseProtonet: inv_d[n,p] = 1 / (mse(f_n, proto_p) + 1e-5), labels[n] = proto_labels[argmax_p inv_d]
// mse = (||f||^2 - 2 f.p + ||p||^2) / 64
//
// Strategy (round 1, correctness-first):
//  - thread = prototype index (256 threads/block), block iterates over rows (grid-stride)
//  - prototype row held in registers as fp64 (128 VGPR); p2 precomputed fp64
//  - feature row read via wave-uniform loads (compiler scalarizes); f2 via lane
//    load + fp64 xor-butterfly (identical value in all lanes/waves)
//  - argmin key computed fully in fp64 to match a float64 numpy reference's
//    argmax exactly; ties broken toward smaller prototype index (jnp.argmax
//    first-occurrence semantics)
//  - inv_d output computed in fp32 (tolerance is 19.84 absolute — trivially met)
//  - labels written as float32 into d_out[N*256 ..] (harness reads whole buffer as fp32)

#define PROTOS 256
#define DIM 64

__global__ __launch_bounds__(256)
void protonet_kernel(const float* __restrict__ feats,
                     const float* __restrict__ protos,
                     const int* __restrict__ plabels,
                     float* __restrict__ out_inv,
                     float* __restrict__ out_lab,
                     int rows_total)
{
    const int p    = threadIdx.x;        // prototype index owned by this thread
    const int lane = threadIdx.x & 63;
    const int wid  = threadIdx.x >> 6;

    // Load my prototype row, convert to fp64 registers, compute ||p||^2 in fp64.
    double prD[DIM];
    double p2 = 0.0;
    {
        const float4* pr = (const float4*)(protos + p * DIM);
        #pragma unroll
        for (int i = 0; i < DIM / 4; ++i) {
            float4 v = pr[i];
            prD[4 * i + 0] = (double)v.x;
            prD[4 * i + 1] = (double)v.y;
            prD[4 * i + 2] = (double)v.z;
            prD[4 * i + 3] = (double)v.w;
        }
        #pragma unroll
        for (int k = 0; k < DIM; ++k) p2 = fma(prD[k], prD[k], p2);
    }

    __shared__ double s_val[4];
    __shared__ int    s_idx[4];

    for (int row = blockIdx.x; row < rows_total; row += gridDim.x) {
        const float* frow = feats + (size_t)row * DIM;

        // ||f||^2 in fp64: each lane loads one element (coalesced 256B), xor-butterfly.
        // All lanes/waves converge to the bit-identical value (commutative pairings).
        float fv = frow[lane];
        double fs = (double)fv * (double)fv;
        #pragma unroll
        for (int s = 32; s > 0; s >>= 1) fs += __shfl_xor(fs, s, 64);

        // cross = dot(f_row, proto_p) in fp64; 4 accumulators to break the fma chain.
        double a0 = 0.0, a1 = 0.0, a2 = 0.0, a3 = 0.0;
        #pragma unroll
        for (int k = 0; k < DIM; k += 4) {
            a0 = fma((double)frow[k + 0], prD[k + 0], a0);
            a1 = fma((double)frow[k + 1], prD[k + 1], a1);
            a2 = fma((double)frow[k + 2], prD[k + 2], a2);
            a3 = fma((double)frow[k + 3], prD[k + 3], a3);
        }
        double cross = (a0 + a1) + (a2 + a3);

        double msed = fs - 2.0 * cross + p2;         // mse * 64, fp64 argmin key
        double mse  = msed * (1.0 / 64.0);
        float  inv  = 1.0f / ((float)mse + 1e-5f);
        out_inv[(size_t)row * PROTOS + p] = inv;      // coalesced: 256 consecutive floats

        // argmin of msed across the 256 threads; tie -> smaller prototype index.
        double bv = msed;
        int    bi = p;
        #pragma unroll
        for (int s = 32; s > 0; s >>= 1) {
            double ov = __shfl_xor(bv, s, 64);
            int    oi = __shfl_xor(bi, s, 64);
            if (ov < bv || (ov == bv && oi < bi)) { bv = ov; bi = oi; }
        }
        if (lane == 0) { s_val[wid] = bv; s_idx[wid] = bi; }
        __syncthreads();
        if (threadIdx.x == 0) {
            double v = s_val[0];
            int    i = s_idx[0];
            #pragma unroll
            for (int w = 1; w < 4; ++w) {
                if (s_val[w] < v || (s_val[w] == v && s_idx[w] < i)) { v = s_val[w]; i = s_idx[w]; }
            }
            out_lab[row] = (float)plabels[i];
        }
        __syncthreads();   // protect s_val/s_idx reuse next row
    }
}

extern "C" void kernel_launch(void* const* d_in, const int* in_sizes, int n_in,
                              void* d_out, int out_size, void* d_ws, size_t ws_size,
                              hipStream_t stream) {
    const float* feats  = (const float*)d_in[0];
    const float* protos = (const float*)d_in[1];
    const int*   plab   = (const int*)d_in[2];
    const int rows = in_sizes[0] / DIM;          // 262144

    float* out_inv = (float*)d_out;
    float* out_lab = out_inv + (size_t)rows * PROTOS;

    dim3 grid(2048), block(256);
    hipLaunchKernelGGL(protonet_kernel, grid, block, 0, stream,
                       feats, protos, plab, out_inv, out_lab, rows);
}

// Round 2
// 740.752 us; speedup vs baseline: 1.4807x; 1.4807x over previous
//
#include <hip/hip_runtime.h>

// BaseProtonet: inv_d[n,p] = 1/(mse(f_n,proto_p)+1e-5), labels[n] = plabels[argmax_p inv_d]
// msed = ||f||^2 - 2 f.p + ||p||^2  (= 64*mse), argmax inv_d == argmin msed.
//
// Round 2: fp32 main pass + fp64 rescue for near-ties.
//  - thread = proto (256/block); prototype row in 64 fp32 VGPRs (128-VGPR cap via
//    __launch_bounds__(256,4) guarantees residency — round 1's fp64 copy spilled).
//  - argmin key packed u32: (float_bits & ~0xFF) | p  (monotone for msed>0; low 8
//    bits = proto idx gives tie->smaller idx). Wave butterfly min + 2nd-min.
//  - rows where (2nd - best) < MARGIN=0.125 (~1.4% of rows; fp32+quant error
//    budget ~0.005 per key) are recomputed block-uniformly with the EXACT fp64
//    recipe that passed round 1 (serial-p2, 4-accumulator dot, xor-butterfly fs).
//  - inv_d tolerance is 19.84 absolute -> fp32 everywhere for the value output.

#define PROTOS 256
#define DIM 64
#define MARGIN 0.125f

__global__ __launch_bounds__(256, 4)
void protonet_kernel(const float* __restrict__ feats,
                     const float* __restrict__ protos,
                     const int* __restrict__ plabels,
                     float* __restrict__ out_inv,
                     float* __restrict__ out_lab,
                     int rows_total)
{
    const int p    = threadIdx.x;
    const int lane = threadIdx.x & 63;
    const int wid  = threadIdx.x >> 6;

    // Prototype row in fp32 registers (64 VGPRs). p2 in fp64 (exact round-1 order)
    // and fp32 (main pass).
    float pr[DIM];
    {
        const float4* prv = (const float4*)(protos + p * DIM);
        #pragma unroll
        for (int i = 0; i < DIM / 4; ++i) {
            float4 v = prv[i];
            pr[4 * i + 0] = v.x; pr[4 * i + 1] = v.y;
            pr[4 * i + 2] = v.z; pr[4 * i + 3] = v.w;
        }
    }
    double p2d = 0.0;
    #pragma unroll
    for (int k = 0; k < DIM; ++k) p2d = fma((double)pr[k], (double)pr[k], p2d);
    float p2f = (float)p2d;

    __shared__ unsigned int s_m1[4], s_m2[4];
    __shared__ double s_dval[4];
    __shared__ int    s_didx[4];
    __shared__ int    s_flag;

    for (int row = blockIdx.x; row < rows_total; row += gridDim.x) {
        const float* frow = feats + (size_t)row * DIM;
        const float4* f4  = (const float4*)frow;

        // ||f||^2 fp32 via lane load + xor butterfly (uniform across waves).
        float fv  = frow[lane];
        float fsf = fv * fv;
        #pragma unroll
        for (int s = 32; s > 0; s >>= 1) fsf += __shfl_xor(fsf, s, 64);

        // dot(f, proto_p) fp32, 4 accumulators.
        float a0 = 0.f, a1 = 0.f, a2 = 0.f, a3 = 0.f;
        #pragma unroll
        for (int i = 0; i < DIM / 4; ++i) {
            float4 x = f4[i];
            a0 = fmaf(x.x, pr[4 * i + 0], a0);
            a1 = fmaf(x.y, pr[4 * i + 1], a1);
            a2 = fmaf(x.z, pr[4 * i + 2], a2);
            a3 = fmaf(x.w, pr[4 * i + 3], a3);
        }
        float cross = (a0 + a1) + (a2 + a3);
        float msed  = fsf - 2.0f * cross + p2f;

        out_inv[(size_t)row * PROTOS + p] = 1.0f / (msed * (1.0f / 64.0f) + 1e-5f);

        // Packed u32 argmin key; wave min + wave 2nd-min.
        unsigned int comb = (__float_as_uint(msed) & 0xFFFFFF00u) | (unsigned int)p;
        unsigned int m1 = comb;
        #pragma unroll
        for (int s = 32; s > 0; s >>= 1) {
            unsigned int o = __shfl_xor(m1, s, 64);
            m1 = (o < m1) ? o : m1;
        }
        unsigned int masked = (comb == m1) ? 0xFFFFFFFFu : comb;
        unsigned int m2 = masked;
        #pragma unroll
        for (int s = 32; s > 0; s >>= 1) {
            unsigned int o = __shfl_xor(m2, s, 64);
            m2 = (o < m2) ? o : m2;
        }
        if (lane == 0) { s_m1[wid] = m1; s_m2[wid] = m2; }
        __syncthreads();

        if (threadIdx.x == 0) {
            unsigned int b1 = 0xFFFFFFFFu, b2 = 0xFFFFFFFFu;
            #pragma unroll
            for (int w = 0; w < 4; ++w) {
                unsigned int u1 = s_m1[w], u2 = s_m2[w];
                unsigned int hi = (b1 > u1) ? b1 : u1;       // loser of the mins
                unsigned int lo2 = (b2 < u2) ? b2 : u2;
                b1 = (b1 < u1) ? b1 : u1;
                b2 = (hi < lo2) ? hi : lo2;
            }
            float v1 = __uint_as_float(b1 & 0xFFFFFF00u);
            float v2 = __uint_as_float(b2 & 0xFFFFFF00u);
            int resc = (v2 - v1) < MARGIN;
            s_flag = resc;
            if (!resc) out_lab[row] = (float)plabels[b1 & 0xFFu];
        }
        __syncthreads();

        if (s_flag) {
            // fp64 rescue — EXACT round-1 recipe (empirically matches np ref).
            float fl   = frow[lane];
            double fsd = (double)fl * (double)fl;
            #pragma unroll
            for (int s = 32; s > 0; s >>= 1) fsd += __shfl_xor(fsd, s, 64);

            double d0 = 0.0, d1 = 0.0, d2 = 0.0, d3 = 0.0;
            #pragma unroll
            for (int k = 0; k < DIM; k += 4) {
                d0 = fma((double)frow[k + 0], (double)pr[k + 0], d0);
                d1 = fma((double)frow[k + 1], (double)pr[k + 1], d1);
                d2 = fma((double)frow[k + 2], (double)pr[k + 2], d2);
                d3 = fma((double)frow[k + 3], (double)pr[k + 3], d3);
            }
            double crossd = (d0 + d1) + (d2 + d3);
            double msedd  = fsd - 2.0 * crossd + p2d;

            double bv = msedd;
            int    bi = p;
            #pragma unroll
            for (int s = 32; s > 0; s >>= 1) {
                double ov = __shfl_xor(bv, s, 64);
                int    oi = __shfl_xor(bi, s, 64);
                if (ov < bv || (ov == bv && oi < bi)) { bv = ov; bi = oi; }
            }
            if (lane == 0) { s_dval[wid] = bv; s_didx[wid] = bi; }
            __syncthreads();
            if (threadIdx.x == 0) {
                double v = s_dval[0];
                int    i = s_didx[0];
                #pragma unroll
                for (int w = 1; w < 4; ++w) {
                    if (s_dval[w] < v || (s_dval[w] == v && s_didx[w] < i)) {
                        v = s_dval[w]; i = s_didx[w];
                    }
                }
                out_lab[row] = (float)plabels[i];
            }
            __syncthreads();
        }
    }
}

extern "C" void kernel_launch(void* const* d_in, const int* in_sizes, int n_in,
                              void* d_out, int out_size, void* d_ws, size_t ws_size,
                              hipStream_t stream) {
    const float* feats  = (const float*)d_in[0];
    const float* protos = (const float*)d_in[1];
    const int*   plab   = (const int*)d_in[2];
    const int rows = in_sizes[0] / DIM;

    float* out_inv = (float*)d_out;
    float* out_lab = out_inv + (size_t)rows * PROTOS;

    dim3 grid(2048), block(256);
    hipLaunchKernelGGL(protonet_kernel, grid, block, 0, stream,
                       feats, protos, plab, out_inv, out_lab, rows);
}